// Round 5
// baseline (690.386 us; speedup 1.0000x reference)
//
#include <hip/hip_runtime.h>

namespace {

constexpr int B = 128, N = 2048, E = 32768;
constexpr int LOG2N = 11, LOG2E = 15;

// ws layout (bytes)
constexpr size_t OFF_H0 = 0;                    // B*N float4 = 4 MB
constexpr size_t OFF_H1 = 4u * 1024 * 1024;     // B*N float4 = 4 MB

// monotone float->uint encoding for atomicMax on logits
__device__ __forceinline__ unsigned enc_f(float f) {
  int u = __float_as_int(f);
  return (unsigned)u ^ (unsigned)((u >> 31) | 0x80000000);
}
__device__ __forceinline__ float dec_f(unsigned k) {
  int u = (k & 0x80000000u) ? (int)(k & 0x7FFFFFFFu) : ~(int)k;
  return __int_as_float(u);
}

// One block per batch. Edge-parallel segment softmax with LDS accumulators.
// No global atomics, no random global writes (R2: global atomics cost 212MB
// writeback; R4: random 8B stores cost 115MB — both ~60B/access HBM tax).
__global__ __launch_bounds__(1024) void layer_kernel(
    const float4* __restrict__ h_in, float4* __restrict__ h_out,
    const int* __restrict__ edge_index, const float* __restrict__ edge_time,
    const float* __restrict__ timestamp,
    const float* __restrict__ tw, const float* __restrict__ tb,
    const float* __restrict__ Wq, const float* __restrict__ Wk,
    const float* __restrict__ Wv, const float* __restrict__ Wo,
    const float* __restrict__ bo) {
  // SoA so random per-edge reads are ds_read_b32 (~2-way alias = free)
  __shared__ float    lh[4][N];   // 32 KB  h staged
  __shared__ unsigned lm[2][N];   // 16 KB  encoded per-head max
  __shared__ float    ls[2][N];   // 16 KB  softmax denominators
  __shared__ float    la[4][N];   // 32 KB  p*v accumulators   => 96 KB total
  int b = blockIdx.x, t = threadIdx.x;

  float twf[4], tbf[4], bof[4], wq[16], wof[16], wk[32], wv[32];
#pragma unroll
  for (int j = 0; j < 4; j++) { twf[j] = tw[j]; tbf[j] = tb[j]; bof[j] = bo[j]; }
#pragma unroll
  for (int j = 0; j < 16; j++) { wq[j] = Wq[j]; wof[j] = Wo[j]; }
#pragma unroll
  for (int j = 0; j < 32; j++) { wk[j] = Wk[j]; wv[j] = Wv[j]; }
  float ts = timestamp[b];

  const float4* hb = h_in + ((size_t)b << LOG2N);
#pragma unroll
  for (int n = t; n < N; n += 1024) {
    float4 h4 = hb[n];
    lh[0][n] = h4.x; lh[1][n] = h4.y; lh[2][n] = h4.z; lh[3][n] = h4.w;
    lm[0][n] = 0u;  lm[1][n] = 0u;
    ls[0][n] = 0.f; ls[1][n] = 0.f;
    la[0][n] = 0.f; la[1][n] = 0.f; la[2][n] = 0.f; la[3][n] = 0.f;
  }
  __syncthreads();

  const int* src_arr = edge_index + ((size_t)(2 * b) << LOG2E);
  const int* dst_arr = src_arr + E;
  const float* et    = edge_time + ((size_t)b << LOG2E);
  const float RS2 = 0.70710678118654752f;

  // ---- pass 1: per-(dst,head) max logit ----
  for (int e = t; e < E; e += 1024) {
    int src = src_arr[e], dst = dst_arr[e];
    float dt = ts - et[e];
    float msg[8];
    msg[0] = lh[0][src]; msg[1] = lh[1][src]; msg[2] = lh[2][src]; msg[3] = lh[3][src];
#pragma unroll
    for (int j = 0; j < 4; j++) msg[4 + j] = __cosf(dt * twf[j] + tbf[j]);
    float k0 = 0, k1 = 0, k2 = 0, k3 = 0;
#pragma unroll
    for (int j = 0; j < 8; j++) {
      k0 += msg[j] * wk[j * 4 + 0]; k1 += msg[j] * wk[j * 4 + 1];
      k2 += msg[j] * wk[j * 4 + 2]; k3 += msg[j] * wk[j * 4 + 3];
    }
    float d0 = lh[0][dst], d1 = lh[1][dst], d2 = lh[2][dst], d3 = lh[3][dst];
    float q0 = d0 * wq[0] + d1 * wq[4] + d2 * wq[8]  + d3 * wq[12];
    float q1 = d0 * wq[1] + d1 * wq[5] + d2 * wq[9]  + d3 * wq[13];
    float q2 = d0 * wq[2] + d1 * wq[6] + d2 * wq[10] + d3 * wq[14];
    float q3 = d0 * wq[3] + d1 * wq[7] + d2 * wq[11] + d3 * wq[15];
    float l0 = (q0 * k0 + q1 * k1) * RS2;
    float l1 = (q2 * k2 + q3 * k3) * RS2;
    atomicMax(&lm[0][dst], enc_f(l0));
    atomicMax(&lm[1][dst], enc_f(l1));
  }
  __syncthreads();

  // ---- pass 2: exp + weighted accumulate ----
  for (int e = t; e < E; e += 1024) {
    int src = src_arr[e], dst = dst_arr[e];
    float dt = ts - et[e];
    float msg[8];
    msg[0] = lh[0][src]; msg[1] = lh[1][src]; msg[2] = lh[2][src]; msg[3] = lh[3][src];
#pragma unroll
    for (int j = 0; j < 4; j++) msg[4 + j] = __cosf(dt * twf[j] + tbf[j]);
    float k0 = 0, k1 = 0, k2 = 0, k3 = 0, v0 = 0, v1 = 0, v2 = 0, v3 = 0;
#pragma unroll
    for (int j = 0; j < 8; j++) {
      k0 += msg[j] * wk[j * 4 + 0]; k1 += msg[j] * wk[j * 4 + 1];
      k2 += msg[j] * wk[j * 4 + 2]; k3 += msg[j] * wk[j * 4 + 3];
      v0 += msg[j] * wv[j * 4 + 0]; v1 += msg[j] * wv[j * 4 + 1];
      v2 += msg[j] * wv[j * 4 + 2]; v3 += msg[j] * wv[j * 4 + 3];
    }
    float d0 = lh[0][dst], d1 = lh[1][dst], d2 = lh[2][dst], d3 = lh[3][dst];
    float q0 = d0 * wq[0] + d1 * wq[4] + d2 * wq[8]  + d3 * wq[12];
    float q1 = d0 * wq[1] + d1 * wq[5] + d2 * wq[9]  + d3 * wq[13];
    float q2 = d0 * wq[2] + d1 * wq[6] + d2 * wq[10] + d3 * wq[14];
    float q3 = d0 * wq[3] + d1 * wq[7] + d2 * wq[11] + d3 * wq[15];
    float l0 = (q0 * k0 + q1 * k1) * RS2;
    float l1 = (q2 * k2 + q3 * k3) * RS2;
    float p0 = __expf(l0 - dec_f(lm[0][dst]));
    float p1 = __expf(l1 - dec_f(lm[1][dst]));
    atomicAdd(&ls[0][dst], p0);
    atomicAdd(&ls[1][dst], p1);
    atomicAdd(&la[0][dst], p0 * v0);
    atomicAdd(&la[1][dst], p0 * v1);
    atomicAdd(&la[2][dst], p1 * v2);
    atomicAdd(&la[3][dst], p1 * v3);
  }
  __syncthreads();

  // ---- epilogue: attn@Wo + residual + relu ----
  float4* ho = h_out + ((size_t)b << LOG2N);
#pragma unroll
  for (int n = t; n < N; n += 1024) {
    float s0 = ls[0][n], s1 = ls[1][n];
    float e0 = (s0 == 0.f) ? 1.f : s0;
    float e1 = (s1 == 0.f) ? 1.f : s1;
    float at0 = la[0][n] / e0, at1 = la[1][n] / e0;
    float at2 = la[2][n] / e1, at3 = la[3][n] / e1;
    float o0 = bof[0] + at0 * wof[0] + at1 * wof[4] + at2 * wof[8]  + at3 * wof[12];
    float o1 = bof[1] + at0 * wof[1] + at1 * wof[5] + at2 * wof[9]  + at3 * wof[13];
    float o2 = bof[2] + at0 * wof[2] + at1 * wof[6] + at2 * wof[10] + at3 * wof[14];
    float o3 = bof[3] + at0 * wof[3] + at1 * wof[7] + at2 * wof[11] + at3 * wof[15];
    ho[n] = make_float4(fmaxf(lh[0][n] + o0, 0.f), fmaxf(lh[1][n] + o1, 0.f),
                        fmaxf(lh[2][n] + o2, 0.f), fmaxf(lh[3][n] + o3, 0.f));
  }
}

__global__ void final_kernel(const float4* __restrict__ h,
                             const int* __restrict__ src_index, const int* __restrict__ dst_index,
                             const float* __restrict__ timestamp,
                             const float* __restrict__ tw,
                             const float* __restrict__ tb,
                             const float* __restrict__ W_lin,
                             const float* __restrict__ b_lin,
                             float* __restrict__ out) {
  int b = threadIdx.x;
  if (b >= B) return;
  float4 sx = h[(((size_t)b) << LOG2N) + src_index[b]];
  float4 dx = h[(((size_t)b) << LOG2N) + dst_index[b]];
  float ts = timestamp[b];
  float f[12];
  f[0] = sx.x; f[1] = sx.y; f[2] = sx.z; f[3] = sx.w;
  f[4] = dx.x; f[5] = dx.y; f[6] = dx.z; f[7] = dx.w;
#pragma unroll
  for (int j = 0; j < 4; j++) f[8 + j] = __cosf(ts * tw[j] + tb[j]);
#pragma unroll
  for (int c = 0; c < 2; c++) {
    float o = b_lin[c];
#pragma unroll
    for (int j = 0; j < 12; j++) o += f[j] * W_lin[j * 2 + c];
    out[b * 2 + c] = o;
  }
}

}  // namespace

extern "C" void kernel_launch(void* const* d_in, const int* in_sizes, int n_in,
                              void* d_out, int out_size, void* d_ws, size_t ws_size,
                              hipStream_t stream) {
  (void)in_sizes; (void)n_in; (void)out_size; (void)ws_size;
  const float* x         = (const float*)d_in[0];
  const int*   edge_idx  = (const int*)d_in[1];
  const float* edge_time = (const float*)d_in[2];
  const float* timestamp = (const float*)d_in[3];
  const int*   src_index = (const int*)d_in[4];
  const int*   dst_index = (const int*)d_in[5];
  const float* time_w    = (const float*)d_in[6];
  const float* time_b    = (const float*)d_in[7];
  const float* Wq        = (const float*)d_in[8];
  const float* Wk        = (const float*)d_in[9];
  const float* Wv        = (const float*)d_in[10];
  const float* Wo        = (const float*)d_in[11];
  const float* bo        = (const float*)d_in[12];
  const float* W_lin     = (const float*)d_in[13];
  const float* b_lin     = (const float*)d_in[14];

  char* ws = (char*)d_ws;
  float4* h0 = (float4*)(ws + OFF_H0);
  float4* h1 = (float4*)(ws + OFF_H1);

  layer_kernel<<<B, 1024, 0, stream>>>((const float4*)x, h1, edge_idx, edge_time, timestamp,
                                       time_w, time_b,
                                       Wq + 0 * 16, Wk + 0 * 32, Wv + 0 * 32,
                                       Wo + 0 * 16, bo + 0 * 4);
  layer_kernel<<<B, 1024, 0, stream>>>(h1, h0, edge_idx, edge_time, timestamp,
                                       time_w, time_b,
                                       Wq + 1 * 16, Wk + 1 * 32, Wv + 1 * 32,
                                       Wo + 1 * 16, bo + 1 * 4);

  final_kernel<<<1, 128, 0, stream>>>(h0, src_index, dst_index, timestamp, time_w, time_b,
                                      W_lin, b_lin, (float*)d_out);
}

// Round 6
// 185.617 us; speedup vs baseline: 3.7194x; 3.7194x over previous
//
#include <hip/hip_runtime.h>

namespace {

constexpr int B = 128, N = 2048, E = 32768;
constexpr int LOG2N = 11, LOG2E = 15;
constexpr int QE = E / 4;          // edges per quarter block = 8192
constexpr int LOG2QE = 13;

// ws layout (bytes)
constexpr size_t OFF_H0 = 0;                     // B*N float4 = 4 MB
constexpr size_t OFF_H1 = 4u * 1024 * 1024;      // B*N float4 = 4 MB
constexpr size_t OFF_S8 = 8u * 1024 * 1024;      // B*4 quarters * QE int2 = 32 MB
constexpr size_t OFF_RP = 40u * 1024 * 1024;     // B*4*(N+1) int ~ 4.2 MB

// One block per (batch, quarter). Builds a per-quarter CSR of (src, dt)
// records entirely in LDS, then streams it out coalesced.
// R2/R4 lesson: random fine-grained global writes/atomics cost ~60B/access
// of HBM writeback. R5 lesson: 8 random LDS atomics/edge serialize the LDS
// pipe (6.5M conflict cycles). Here: 2 LDS atomics/edge, streaming global IO.
__global__ __launch_bounds__(1024) void sort_kernel(const int* __restrict__ edge_index,
                                                    const float* __restrict__ edge_time,
                                                    const float* __restrict__ timestamp,
                                                    int2* __restrict__ sorted8,
                                                    int* __restrict__ row_ptr) {
  __shared__ int  cnt[N];        // 8 KB: counts -> cursors
  __shared__ int  partial[1024]; // 4 KB
  __shared__ int2 rec[QE];       // 64 KB: local CSR records
  int blk = blockIdx.x, b = blk >> 2, q = blk & 3, t = threadIdx.x;

  cnt[t] = 0; cnt[t + 1024] = 0;
  __syncthreads();

  const int* src_arr = edge_index + (((size_t)(2 * b)) << LOG2E) + q * QE;
  const int* dst_arr = edge_index + (((size_t)(2 * b + 1)) << LOG2E) + q * QE;
  const float* et    = edge_time + (((size_t)b) << LOG2E) + q * QE;
  float ts = timestamp[b];

  // hist
  for (int e = t; e < QE; e += 1024) atomicAdd(&cnt[dst_arr[e]], 1);
  __syncthreads();

  // exclusive scan of 2048 counts (2 per thread)
  int i0 = 2 * t, i1 = 2 * t + 1;
  int l0 = cnt[i0], l1 = cnt[i1];
  int sum = l0 + l1;
  partial[t] = sum;
  __syncthreads();
  for (int d = 1; d < 1024; d <<= 1) {
    int v = (t >= d) ? partial[t - d] : 0;
    __syncthreads();
    partial[t] += v;
    __syncthreads();
  }
  int run = partial[t] - sum;
  int run2 = run + l0;
  int* rp = row_ptr + (size_t)blk * (N + 1);
  rp[i0] = run;
  rp[i1] = run2;
  if (t == 1023) rp[N] = QE;
  cnt[i0] = run;   // becomes cursor
  cnt[i1] = run2;
  __syncthreads();

  // scatter into LDS CSR
  for (int e = t; e < QE; e += 1024) {
    int dst = dst_arr[e];
    int src = src_arr[e];
    float dt = ts - et[e];
    int pos = atomicAdd(&cnt[dst], 1);
    rec[pos] = make_int2(src, __float_as_int(dt));
  }
  __syncthreads();

  // coalesced stream-out (int4 = 2 records)
  const int4* rec4 = (const int4*)rec;
  int4* out4 = (int4*)(sorted8 + (((size_t)blk) << LOG2QE));
#pragma unroll
  for (int i = t; i < QE / 2; i += 1024) out4[i] = rec4[i];
}

// 2 blocks per batch, one thread per node; h staged in LDS; node walks its
// 4 quarter-CSR segments with one continuous online softmax.
__global__ __launch_bounds__(1024) void layer_kernel(const float4* __restrict__ h_in,
                                                     float4* __restrict__ h_out,
                                                     const int* __restrict__ row_ptr,
                                                     const int2* __restrict__ sorted8,
                                                     const float* __restrict__ tw,
                                                     const float* __restrict__ tb,
                                                     const float* __restrict__ Wq,
                                                     const float* __restrict__ Wk,
                                                     const float* __restrict__ Wv,
                                                     const float* __restrict__ Wo,
                                                     const float* __restrict__ bo) {
  __shared__ float4 lh[N];  // 32 KB
  int blk = blockIdx.x, b = blk >> 1, half = blk & 1, t = threadIdx.x;

  const float4* hb = h_in + (((size_t)b) << LOG2N);
  lh[t] = hb[t];
  lh[t + 1024] = hb[t + 1024];

  float twf[4], tbf[4], bof[4], wq[16], wof[16], wk[32], wv[32];
#pragma unroll
  for (int j = 0; j < 4; j++) { twf[j] = tw[j]; tbf[j] = tb[j]; bof[j] = bo[j]; }
#pragma unroll
  for (int j = 0; j < 16; j++) { wq[j] = Wq[j]; wof[j] = Wo[j]; }
#pragma unroll
  for (int j = 0; j < 32; j++) { wk[j] = Wk[j]; wv[j] = Wv[j]; }
  __syncthreads();

  int n = half * 1024 + t;
  float4 hn = lh[n];
  float q0 = hn.x * wq[0] + hn.y * wq[4] + hn.z * wq[8]  + hn.w * wq[12];
  float q1 = hn.x * wq[1] + hn.y * wq[5] + hn.z * wq[9]  + hn.w * wq[13];
  float q2 = hn.x * wq[2] + hn.y * wq[6] + hn.z * wq[10] + hn.w * wq[14];
  float q3 = hn.x * wq[3] + hn.y * wq[7] + hn.z * wq[11] + hn.w * wq[15];

  float m0 = -INFINITY, m1 = -INFINITY;
  float s0 = 0.f, s1 = 0.f, a00 = 0.f, a01 = 0.f, a10 = 0.f, a11 = 0.f;
  const float RS2 = 0.70710678118654752f;

#pragma unroll
  for (int q = 0; q < 4; ++q) {
    int qblk = b * 4 + q;
    const int* rp = row_ptr + (size_t)qblk * (N + 1);
    const int2* srt = sorted8 + (((size_t)qblk) << LOG2QE);
    int beg = rp[n], end = rp[n + 1];
    for (int i = beg; i < end; ++i) {
      int2 rc = srt[i];
      float dt = __int_as_float(rc.y);
      float4 hs = lh[rc.x];
      float msg[8];
      msg[0] = hs.x; msg[1] = hs.y; msg[2] = hs.z; msg[3] = hs.w;
#pragma unroll
      for (int j = 0; j < 4; j++) msg[4 + j] = __cosf(dt * twf[j] + tbf[j]);
      float k0 = 0, k1 = 0, k2 = 0, k3 = 0, v0 = 0, v1 = 0, v2 = 0, v3 = 0;
#pragma unroll
      for (int j = 0; j < 8; j++) {
        k0 += msg[j] * wk[j * 4 + 0]; k1 += msg[j] * wk[j * 4 + 1];
        k2 += msg[j] * wk[j * 4 + 2]; k3 += msg[j] * wk[j * 4 + 3];
        v0 += msg[j] * wv[j * 4 + 0]; v1 += msg[j] * wv[j * 4 + 1];
        v2 += msg[j] * wv[j * 4 + 2]; v3 += msg[j] * wv[j * 4 + 3];
      }
      float l0 = (q0 * k0 + q1 * k1) * RS2;  // head0: c=0,1
      float l1 = (q2 * k2 + q3 * k3) * RS2;  // head1: c=2,3
      float nm0 = fmaxf(m0, l0);
      float sc0 = __expf(m0 - nm0);
      float p0  = __expf(l0 - nm0);
      s0 = s0 * sc0 + p0; a00 = a00 * sc0 + p0 * v0; a01 = a01 * sc0 + p0 * v1; m0 = nm0;
      float nm1 = fmaxf(m1, l1);
      float sc1 = __expf(m1 - nm1);
      float p1  = __expf(l1 - nm1);
      s1 = s1 * sc1 + p1; a10 = a10 * sc1 + p1 * v2; a11 = a11 * sc1 + p1 * v3; m1 = nm1;
    }
  }
  float d0 = (s0 == 0.f) ? 1.f : s0;
  float d1 = (s1 == 0.f) ? 1.f : s1;
  float at0 = a00 / d0, at1 = a01 / d0, at2 = a10 / d1, at3 = a11 / d1;
  float o0 = bof[0] + at0 * wof[0] + at1 * wof[4] + at2 * wof[8]  + at3 * wof[12];
  float o1 = bof[1] + at0 * wof[1] + at1 * wof[5] + at2 * wof[9]  + at3 * wof[13];
  float o2 = bof[2] + at0 * wof[2] + at1 * wof[6] + at2 * wof[10] + at3 * wof[14];
  float o3 = bof[3] + at0 * wof[3] + at1 * wof[7] + at2 * wof[11] + at3 * wof[15];
  h_out[(((size_t)b) << LOG2N) + n] =
      make_float4(fmaxf(hn.x + o0, 0.f), fmaxf(hn.y + o1, 0.f),
                  fmaxf(hn.z + o2, 0.f), fmaxf(hn.w + o3, 0.f));
}

__global__ void final_kernel(const float4* __restrict__ h,
                             const int* __restrict__ src_index, const int* __restrict__ dst_index,
                             const float* __restrict__ timestamp,
                             const float* __restrict__ tw,
                             const float* __restrict__ tb,
                             const float* __restrict__ W_lin,
                             const float* __restrict__ b_lin,
                             float* __restrict__ out) {
  int b = threadIdx.x;
  if (b >= B) return;
  float4 sx = h[(((size_t)b) << LOG2N) + src_index[b]];
  float4 dx = h[(((size_t)b) << LOG2N) + dst_index[b]];
  float ts = timestamp[b];
  float f[12];
  f[0] = sx.x; f[1] = sx.y; f[2] = sx.z; f[3] = sx.w;
  f[4] = dx.x; f[5] = dx.y; f[6] = dx.z; f[7] = dx.w;
#pragma unroll
  for (int j = 0; j < 4; j++) f[8 + j] = __cosf(ts * tw[j] + tb[j]);
#pragma unroll
  for (int c = 0; c < 2; c++) {
    float o = b_lin[c];
#pragma unroll
    for (int j = 0; j < 12; j++) o += f[j] * W_lin[j * 2 + c];
    out[b * 2 + c] = o;
  }
}

}  // namespace

extern "C" void kernel_launch(void* const* d_in, const int* in_sizes, int n_in,
                              void* d_out, int out_size, void* d_ws, size_t ws_size,
                              hipStream_t stream) {
  (void)in_sizes; (void)n_in; (void)out_size; (void)ws_size;
  const float* x         = (const float*)d_in[0];
  const int*   edge_idx  = (const int*)d_in[1];
  const float* edge_time = (const float*)d_in[2];
  const float* timestamp = (const float*)d_in[3];
  const int*   src_index = (const int*)d_in[4];
  const int*   dst_index = (const int*)d_in[5];
  const float* time_w    = (const float*)d_in[6];
  const float* time_b    = (const float*)d_in[7];
  const float* Wq        = (const float*)d_in[8];
  const float* Wk        = (const float*)d_in[9];
  const float* Wv        = (const float*)d_in[10];
  const float* Wo        = (const float*)d_in[11];
  const float* bo        = (const float*)d_in[12];
  const float* W_lin     = (const float*)d_in[13];
  const float* b_lin     = (const float*)d_in[14];

  char* ws = (char*)d_ws;
  float4* h0      = (float4*)(ws + OFF_H0);
  float4* h1      = (float4*)(ws + OFF_H1);
  int2*   sorted8 = (int2*)(ws + OFF_S8);
  int*    row_ptr = (int*)(ws + OFF_RP);

  sort_kernel<<<4 * B, 1024, 0, stream>>>(edge_idx, edge_time, timestamp, sorted8, row_ptr);

  layer_kernel<<<2 * B, 1024, 0, stream>>>((const float4*)x, h1, row_ptr, sorted8,
                                           time_w, time_b,
                                           Wq + 0 * 16, Wk + 0 * 32, Wv + 0 * 32,
                                           Wo + 0 * 16, bo + 0 * 4);
  layer_kernel<<<2 * B, 1024, 0, stream>>>(h1, h0, row_ptr, sorted8,
                                           time_w, time_b,
                                           Wq + 1 * 16, Wk + 1 * 32, Wv + 1 * 32,
                                           Wo + 1 * 16, bo + 1 * 4);

  final_kernel<<<1, 128, 0, stream>>>(h0, src_index, dst_index, timestamp, time_w, time_b,
                                      W_lin, b_lin, (float*)d_out);
}